// Round 5
// baseline (2561.539 us; speedup 1.0000x reference)
//
#include <hip/hip_runtime.h>

#define T_ 64

typedef __attribute__((ext_vector_type(4))) float f32x4;
typedef __attribute__((ext_vector_type(8))) short s16x8;

__device__ __forceinline__ unsigned short f2bf(float f) {
  unsigned u = __float_as_uint(f);
  u = (u + 0x7FFFu + ((u >> 16) & 1u)) >> 16;
  return (unsigned short)u;
}
__device__ __forceinline__ float bf2f(unsigned short h) {
  return __uint_as_float(((unsigned)h) << 16);
}
__device__ __forceinline__ float eluf(float x) { return x > 0.f ? x : __expf(x) - 1.f; }
__device__ __forceinline__ float sigmf(float x) { return 1.f / (1.f + __expf(-x)); }
__device__ __forceinline__ float tanh_(float x) {
  float xx = fminf(fmaxf(x, -30.f), 30.f);
  float e = __expf(-2.f * xx);
  return (1.f - e) / (1.f + e);
}
__device__ __forceinline__ float softpf(float x) {
  return x > 20.f ? x : __logf(1.f + __expf(x));
}

// ---- pk layout (u16 offsets) ----
#define OPW1   0         // img1  KT2 NT13 : 13312
#define OPWI   13312     // gru_wi gate-pad NT40 KT7 : 143360
#define OPWH   156672    // gru_wh NT40 KT7 : 143360
#define OPO1D  300032    // obs1_w deter KT7 NT13 : 46592
#define OPO2   346624    // obs2 KT7 NT4 : 14336
#define OPI2   360960    // img2 KT7 NT13 : 46592 (post)
#define OPI3   407552    // img3 KT7 NT4 : 14336 (post)
#define OWIWT  421888    // wi k=192..199 transposed [640][8] : 5120
#define OO1DWT 427008    // o1d k-rem [208][8] : 1664
#define OI1WT  428672    // img1 k=32..39 [208][8] : 1664
#define OO2WT  430336    // obs2 k-rem [64][8] : 512
#define PK_U16 430848

#define OFF_PK  26214400
#define OFF_SWZ 27076096

// B-frag pack: idx=((nt*KT+kt)*64+lane)*8+j ; holds W[k][n],
// n=nt*16+(lane&15), k=kt*32+(lane>>4)*8+j, zero-padded.
__device__ void pack_mat(int idx, int stride, const float* __restrict__ W,
                         int K, int N, int KT, int NT, unsigned short* __restrict__ dst) {
  int total = KT * NT * 512;
  for (int i = idx; i < total; i += stride) {
    int j = i & 7, l = (i >> 3) & 63, rem = i >> 9;
    int kt = rem % KT, nt = rem / KT;
    int n = nt * 16 + (l & 15), k = kt * 32 + (l >> 4) * 8 + j;
    float v = (k < K && n < N) ? W[(size_t)k * N + n] : 0.f;
    dst[i] = f2bf(v);
  }
}

// GRU gate-padded: packed col c = g*208+u (g=0,1,2 -> r,z,n), NT=40.
__device__ void pack_gru40(int idx, int stride, const float* __restrict__ W,
                           unsigned short* __restrict__ dst) {
  int total = 40 * 7 * 512;
  for (int i = idx; i < total; i += stride) {
    int j = i & 7, l = (i >> 3) & 63, rem = i >> 9;
    int kt = rem % 7, nt = rem / 7;
    int c = nt * 16 + (l & 15);
    int g = c / 208, u = c - g * 208;
    int k = kt * 32 + (l >> 4) * 8 + j;
    float v = (g < 3 && u < 200 && k < 200) ? W[(size_t)k * 600 + g * 200 + u] : 0.f;
    dst[i] = f2bf(v);
  }
}

__global__ void prep_weights(const float* __restrict__ w1, const float* __restrict__ wi,
                             const float* __restrict__ wh, const float* __restrict__ i2,
                             const float* __restrict__ i3, const float* __restrict__ obs1w,
                             const float* __restrict__ o2,
                             unsigned short* __restrict__ pk,
                             unsigned short* __restrict__ swz) {
  int idx = blockIdx.x * blockDim.x + threadIdx.x;
  int stride = gridDim.x * blockDim.x;
  pack_mat(idx, stride, w1, 40, 200, 2, 13, pk + OPW1);
  pack_gru40(idx, stride, wi, pk + OPWI);
  pack_gru40(idx, stride, wh, pk + OPWH);
  pack_mat(idx, stride, obs1w, 200, 200, 7, 13, pk + OPO1D);
  pack_mat(idx, stride, o2, 200, 60, 7, 4, pk + OPO2);
  pack_mat(idx, stride, i2, 200, 200, 7, 13, pk + OPI2);
  pack_mat(idx, stride, i3, 200, 60, 7, 4, pk + OPI3);
  // k-remainder transposed blocks (k = 192..199 / 32..39), [cols][8]
  for (int i = idx; i < 5120; i += stride) {        // wiWT [640][8]
    int c = i >> 3, j = i & 7;
    int g = c / 208, u = c - g * 208;
    pk[OWIWT + i] = f2bf((g < 3 && u < 200) ? wi[(size_t)(192 + j) * 600 + g * 200 + u] : 0.f);
  }
  for (int i = idx; i < 1664; i += stride) {        // o1dWT [208][8]
    int c = i >> 3, j = i & 7;
    pk[OO1DWT + i] = f2bf((c < 200) ? obs1w[(size_t)(192 + j) * 200 + c] : 0.f);
  }
  for (int i = idx; i < 1664; i += stride) {        // i1WT [208][8]
    int c = i >> 3, j = i & 7;
    pk[OI1WT + i] = f2bf((c < 200) ? w1[(size_t)(32 + j) * 200 + c] : 0.f);
  }
  for (int i = idx; i < 512; i += stride) {         // o2WT [64][8]
    int c = i >> 3, j = i & 7;
    pk[OO2WT + i] = f2bf((c < 60) ? o2[(size_t)(192 + j) * 60 + c] : 0.f);
  }
  // swz for emb_gemm (validated layout)
  for (int i = idx; i < 212992; i += stride) {
    int j = i & 7, l = (i >> 3) & 63, rem = i >> 9;
    int nt = rem % 13, kc = rem / 13;
    int k = kc * 32 + ((l >> 4) * 8) + j;
    int n = nt * 16 + (l & 15);
    float v = (n < 200) ? obs1w[(size_t)(200 + k) * 200 + n] : 0.0f;
    swz[i] = f2bf(v);
  }
}

// --------------------------------------------------------------------------
// emb_pre = embed @ obs1_w[200:,:] + obs1_b   (validated round-1 kernel)
// --------------------------------------------------------------------------
__global__ __launch_bounds__(256) void emb_gemm(const float* __restrict__ embed,
                                                const float* __restrict__ obs1b,
                                                const unsigned short* __restrict__ swz,
                                                unsigned short* __restrict__ emb_pre) {
  __shared__ __align__(16) unsigned short lds_A[64][40];
  int tid = threadIdx.x;
  int lane = tid & 63, w = tid >> 6;
  int R0 = blockIdx.x * 64;
  int tt = R0 >> 10;
  int bb = R0 & 1023;

  f32x4 acc[13];
#pragma unroll
  for (int nt = 0; nt < 13; ++nt) acc[nt] = (f32x4){0.f, 0.f, 0.f, 0.f};

  int i_row = tid >> 2, cg = tid & 3;
  const float* arow = embed + ((size_t)(bb + i_row) * 64 + tt) * 1024 + cg * 8;

  for (int kc = 0; kc < 32; ++kc) {
    __syncthreads();
    {
      const float* p = arow + kc * 32;
      f32x4 a0 = *(const f32x4*)p;
      f32x4 a1 = *(const f32x4*)(p + 4);
      unsigned short* dst = &lds_A[i_row][cg * 8];
      dst[0] = f2bf(a0[0]); dst[1] = f2bf(a0[1]); dst[2] = f2bf(a0[2]); dst[3] = f2bf(a0[3]);
      dst[4] = f2bf(a1[0]); dst[5] = f2bf(a1[1]); dst[6] = f2bf(a1[2]); dst[7] = f2bf(a1[3]);
    }
    __syncthreads();
    s16x8 af = *(const s16x8*)&lds_A[w * 16 + (lane & 15)][(lane >> 4) * 8];
    const unsigned short* bp = swz + (size_t)kc * 6656 + (size_t)lane * 8;
#pragma unroll
    for (int nt = 0; nt < 13; ++nt) {
      s16x8 bfv = *(const s16x8*)(bp + nt * 512);
      acc[nt] = __builtin_amdgcn_mfma_f32_16x16x32_bf16(af, bfv, acc[nt], 0, 0, 0);
    }
  }
  int r0 = R0 + w * 16 + ((lane >> 4) << 2);
  int c0 = lane & 15;
#pragma unroll
  for (int nt = 0; nt < 13; ++nt) {
    int n = nt * 16 + c0;
    if (n < 200) {
      float bv = obs1b[n];
#pragma unroll
      for (int rr = 0; rr < 4; ++rr)
        emb_pre[(size_t)(r0 + rr) * 200 + n] = f2bf(acc[nt][rr] + bv);
    }
  }
}

// --------------------------------------------------------------------------
// Scan v5: v4 + f32 deter carry in persistent regs + action prefetch fix.
// --------------------------------------------------------------------------
#define LGKM0  asm volatile("s_waitcnt lgkmcnt(0)" ::: "memory")
#define MEMCLB asm volatile("" ::: "memory")
#define BAR()  __builtin_amdgcn_s_barrier()

typedef __attribute__((address_space(3))) unsigned int u32_lds;
typedef const __attribute__((address_space(1))) unsigned int u32_glb;

__device__ __forceinline__ void gll16(const unsigned short* g, unsigned short* l, int lane) {
  __builtin_amdgcn_global_load_lds((u32_glb*)(g + lane * 8), (u32_lds*)l, 16, 0, 0);
}

__device__ __forceinline__ void waitv(int n) {
  if (n >= 15)     asm volatile("s_waitcnt vmcnt(15)" ::: "memory");
  else if (n == 4) asm volatile("s_waitcnt vmcnt(4)" ::: "memory");
  else if (n == 2) asm volatile("s_waitcnt vmcnt(2)" ::: "memory");
  else             asm volatile("s_waitcnt vmcnt(1)" ::: "memory");
}

__device__ __forceinline__ const unsigned short* tile_addr(int w, int ni1, int no1d,
                                                           int tau,
                                                           const unsigned short* pk) {
  int t = tau;
  if (t < ni1) return pk + OPW1 + ((w + 8 * t) * 2) * 512;          // img1 kt0
  t -= ni1;
  if (t < 30) return pk + OPWI + ((w + 8 * (t / 6)) * 7 + (t % 6)) * 512;
  t -= 30;
  if (t < no1d) return pk + OPO1D + ((w + 8 * (t / 6)) * 7 + (t % 6)) * 512;
  t -= no1d;
  return pk + OPO2 + (w * 7 + t) * 512;                              // obs2 (w<4)
}

__device__ __forceinline__ void issue_b(int bk, int w, int ni1, int no1d, int Nreal,
                                        int lastb, int off, const unsigned short* pk,
                                        unsigned short (*ringw)[512], int lane) {
  int t0, t1, o;
  if (bk <= lastb) { t0 = 4 * bk; t1 = (t0 + 4 < Nreal) ? t0 + 4 : Nreal; o = off; }
  else { t0 = 4 * (bk - lastb - 1); t1 = t0 + 4; o = (off + Nreal) & 7; }
  for (int tt = t0; tt < t1; ++tt)
    gll16(tile_addr(w, ni1, no1d, tt, pk), &ringw[(tt + o) & 7][0], lane);
}

#define MFMA16(A, B, C) __builtin_amdgcn_mfma_f32_16x16x32_bf16((A), (B), (C), 0, 0, 0)
#define RING(tau) (*(const s16x8*)&ringw[((tau) + off) & 7][lane * 8])
#define WVAL(tau) ((tau) < 8 ? 15 : (((((tau) >> 2) + 1) == lastb && tailsz < 4) ? tailsz : 4))
#define PREI(tau) do { if (((tau) & 3) == 0) waitv(WVAL(tau)); } while (0)
#define POSTI(tau) do { if ((((tau) & 3) == 3) || ((tau) == Nreal - 1)) { \
    LGKM0; issue_b(((tau) >> 2) + 2, w, ni1, no1d, Nreal, lastb, off, pk, ringw, lane); } } while (0)

__global__ __launch_bounds__(512, 2) void scan_v5(
    const float* __restrict__ action, const float* __restrict__ eps_post,
    const float* __restrict__ img1_b, const float* __restrict__ gru_bi,
    const float* __restrict__ gru_bh, const float* __restrict__ obs2_b,
    const unsigned short* __restrict__ pk, const unsigned short* __restrict__ emb_pre,
    float* __restrict__ out) {

  __shared__ __align__(16) unsigned short ring[8][8][512];   // 64 KB
  __shared__ __align__(16) unsigned short l_wiWT[640][8];
  __shared__ __align__(16) unsigned short l_o1dWT[208][8];
  __shared__ __align__(16) unsigned short l_i1WT[208][8];
  __shared__ __align__(16) unsigned short l_o2WT[64][8];
  __shared__ __align__(16) unsigned short zblk[8];
  __shared__ __align__(16) unsigned short xoA[28][16][8];    // xA union o1A
  __shared__ __align__(16) unsigned short dA[28][16][8];
  __shared__ __align__(16) unsigned short sA[8][16][8];
  __shared__ __align__(16) float s_rz[400][16];              // union outbuf [16][292]
  __shared__ __align__(16) float s_in[200][16];
  __shared__ __align__(16) float s_hn[200][16];
  __shared__ __align__(16) float s_o[60][20];

  const int tid = threadIdx.x;
  const int lane = tid & 63;
  const int w = tid >> 6;
  const int arow = lane & 15;
  const int kg = lane >> 4;
  const int b0 = blockIdx.x * 16;
  unsigned short (*ringw)[512] = ring[w];
  float* outbuf = (float*)s_rz;

  const int colA = w * 16 + arow;                 // < 128
  const int colB = (w + 8) * 16 + arow;           // 128..255
  const int colBc = colB < 200 ? colB : 199;
  const int col5 = (w < 4) ? (w * 16 + arow) : 0; // obs2 col (w<4)

  const int ni1 = (w < 5) ? 2 : 1;
  const int no1d = (w < 5) ? 12 : 6;
  const int no2 = (w < 4) ? 6 : 0;
  const int Nreal = ni1 + 30 + no1d + no2;        // 50 / 44 / 37
  const int lastb = (Nreal - 1) >> 2;             // 12 / 10 / 9
  const int tailsz = Nreal - 4 * lastb;           // 2 / 4 / 1

  // ---------------- prologue ----------------
  for (int i = tid; i < 3584; i += 512) {
    ((unsigned short*)xoA)[i] = 0;
    ((unsigned short*)dA)[i] = 0;
  }
  for (int i = tid; i < 1024; i += 512) ((unsigned short*)sA)[i] = 0;
  for (int i = tid; i < 5120; i += 512) ((unsigned short*)l_wiWT)[i] = pk[OWIWT + i];
  for (int i = tid; i < 1664; i += 512) ((unsigned short*)l_o1dWT)[i] = pk[OO1DWT + i];
  for (int i = tid; i < 1664; i += 512) ((unsigned short*)l_i1WT)[i] = pk[OI1WT + i];
  for (int i = tid; i < 512; i += 512) ((unsigned short*)l_o2WT)[i] = pk[OO2WT + i];
  if (tid < 8) zblk[tid] = 0;

  // wh resident B-fragments
  s16x8 whR[5][7];
#pragma unroll
  for (int i = 0; i < 5; ++i)
#pragma unroll
    for (int kt = 0; kt < 7; ++kt)
      whR[i][kt] = *(const s16x8*)(pk + OPWH + (size_t)(((w + 8 * i) * 7 + kt) * 512) + lane * 8);

  // biases
  float b1a = img1_b[colA];
  float b1b = (w < 5 && colB < 200) ? img1_b[colB] : 0.f;
  float bi_[5], bh_[5];
#pragma unroll
  for (int i = 0; i < 5; ++i) {
    int nt = w + 8 * i;
    int g = nt / 13, u = (nt % 13) * 16 + arow;
    bool vld = (nt <= 38) && (u < 200);
    bi_[i] = vld ? gru_bi[g * 200 + u] : 0.f;
    bh_[i] = vld ? gru_bh[g * 200 + u] : 0.f;
  }
  float b5 = (w < 4 && col5 < 60) ? obs2_b[col5] : 0.f;

  // aux pipeline regs for t=0 / t=1
  unsigned short e_[8];
  {
    size_t eb = (size_t)b0 * 200;
#pragma unroll
    for (int rr = 0; rr < 4; ++rr) {
      e_[rr] = emb_pre[eb + (size_t)(kg * 4 + rr) * 200 + colA];
      e_[4 + rr] = emb_pre[eb + (size_t)(kg * 4 + rr) * 200 + colBc];
    }
  }
  float eps_reg = 0.f, act_reg = 0.f;
  if (tid < 480) eps_reg = eps_post[((size_t)(b0 + tid / 30)) * 30 + tid % 30];
  float a0v = 0.f;
  if (lane < 20) {
    int slot = w * 20 + lane;
    a0v = action[((size_t)(b0 + slot / 10) * T_) * 10 + slot % 10];
  }
  __syncthreads();
  if (lane < 20) {
    int slot = w * 20 + lane, kk = slot % 10;
    sA[(30 + kk) >> 3][slot / 10][(30 + kk) & 7] = f2bf(a0v);
  }
  if (lane < 20) {
    int slot = w * 20 + lane;
    act_reg = action[((size_t)(b0 + slot / 10) * T_ + 1) * 10 + slot % 10];
  }
  // persistent f32 deter carry: thread owns (uA=tid>>2, rgA=tid&3) and
  // (uB=uA+128, rgB) for tid<288 — fixed ownership across all t.
  f32x4 dvA = {0.f, 0.f, 0.f, 0.f};
  f32x4 dvB = {0.f, 0.f, 0.f, 0.f};
  __syncthreads();
  int off = 0;
  issue_b(0, w, ni1, no1d, Nreal, lastb, off, pk, ringw, lane);
  issue_b(1, w, ni1, no1d, Nreal, lastb, off, pk, ringw, lane);
  asm volatile("s_waitcnt vmcnt(0)" ::: "memory");
  __syncthreads();

  // ---------------- T loop ----------------
  for (int t = 0; t < T_; ++t) {
    // ---- S1: x = elu([stoch|act]@img1 + b1) ----
    PREI(0);
    s16x8 a0 = *(const s16x8*)&sA[kg][arow][0];
    s16x8 a1 = *(const s16x8*)&sA[4 + kg][arow][0];
    {
      s16x8 B0 = RING(0);
      f32x4 acc = {b1a, b1a, b1a, b1a};
      acc = MFMA16(a0, B0, acc);
      s16x8 B1 = *(const s16x8*)((kg == 0) ? &l_i1WT[colA][0] : &zblk[0]);
      acc = MFMA16(a1, B1, acc);
#pragma unroll
      for (int rr = 0; rr < 4; ++rr)
        xoA[colA >> 3][kg * 4 + rr][colA & 7] = f2bf(eluf(acc[rr]));
    }
    if (w < 5) {
      s16x8 B0 = RING(1);
      f32x4 acc = {b1b, b1b, b1b, b1b};
      acc = MFMA16(a0, B0, acc);
      s16x8 B1 = *(const s16x8*)((kg == 0) ? &l_i1WT[colB][0] : &zblk[0]);
      acc = MFMA16(a1, B1, acc);
      if (colB < 200) {
#pragma unroll
        for (int rr = 0; rr < 4; ++rr)
          xoA[colB >> 3][kg * 4 + rr][colB & 7] = f2bf(eluf(acc[rr]));
      }
    }
    BAR();

    // ---- S2: gi = x@wi (stream) ; gh = deter@wh (regs) ----
    {
      s16x8 ax[7], ad[7];
#pragma unroll
      for (int kt = 0; kt < 7; ++kt) {
        ax[kt] = *(const s16x8*)&xoA[kt * 4 + kg][arow][0];
        ad[kt] = *(const s16x8*)&dA[kt * 4 + kg][arow][0];
      }
#pragma unroll
      for (int i = 0; i < 5; ++i) {
        int nt = w + 8 * i;
        f32x4 ah = {bh_[i], bh_[i], bh_[i], bh_[i]};
#pragma unroll
        for (int kt = 0; kt < 7; ++kt) ah = MFMA16(ad[kt], whR[i][kt], ah);
        f32x4 ai = {bi_[i], bi_[i], bi_[i], bi_[i]};
#pragma unroll
        for (int q = 0; q < 6; ++q) {
          int tau = ni1 + i * 6 + q;
          PREI(tau);
          s16x8 Bv = RING(tau);
          ai = MFMA16(ax[q], Bv, ai);
          POSTI(tau);
        }
        {
          int c = nt * 16 + arow;  // < 640
          const unsigned short* wp = (kg == 0) ? &l_wiWT[c][0] : &zblk[0];
          s16x8 B6 = *(const s16x8*)wp;
          ai = MFMA16(ax[6], B6, ai);
        }
        int g = nt / 13, u = (nt % 13) * 16 + arow;
        if (nt <= 38 && u < 200) {
          if (g < 2) {
            f32x4 s = ai + ah;
            *(f32x4*)&s_rz[g * 200 + u][kg * 4] = s;
          } else {
            *(f32x4*)&s_in[u][kg * 4] = ai;
            *(f32x4*)&s_hn[u][kg * 4] = ah;
          }
        }
      }
    }
    BAR();

    // ---- S3a: read GRU inputs ----
    int uA = tid >> 2, rgA = tid & 3;
    f32x4 rz0a = *(const f32x4*)&s_rz[uA][rgA * 4];
    f32x4 rz1a = *(const f32x4*)&s_rz[200 + uA][rgA * 4];
    f32x4 ina = *(const f32x4*)&s_in[uA][rgA * 4];
    f32x4 hna = *(const f32x4*)&s_hn[uA][rgA * 4];
    bool hasB = tid < 288;
    int uB = uA + 128, rgB = rgA;
    f32x4 rz0b = {0,0,0,0}, rz1b = {0,0,0,0}, inb = {0,0,0,0}, hnb = {0,0,0,0};
    if (hasB) {
      rz0b = *(const f32x4*)&s_rz[uB][rgB * 4];
      rz1b = *(const f32x4*)&s_rz[200 + uB][rgB * 4];
      inb = *(const f32x4*)&s_in[uB][rgB * 4];
      hnb = *(const f32x4*)&s_hn[uB][rgB * 4];
    }
    BAR();
    // ---- S3b: GRU compute on f32 carry; write dA + outbuf deter ----
    {
#pragma unroll
      for (int rr = 0; rr < 4; ++rr) {
        float r = sigmf(rz0a[rr]);
        float z = sigmf(rz1a[rr]);
        float n = tanh_(ina[rr] + r * hna[rr]);
        dvA[rr] = (1.f - z) * n + z * dvA[rr];
      }
#pragma unroll
      for (int rr = 0; rr < 4; ++rr) {
        dA[uA >> 3][rgA * 4 + rr][uA & 7] = f2bf(dvA[rr]);
        outbuf[(rgA * 4 + rr) * 292 + 90 + uA] = dvA[rr];
      }
      if (hasB) {
#pragma unroll
        for (int rr = 0; rr < 4; ++rr) {
          float r = sigmf(rz0b[rr]);
          float z = sigmf(rz1b[rr]);
          float n = tanh_(inb[rr] + r * hnb[rr]);
          dvB[rr] = (1.f - z) * n + z * dvB[rr];
        }
#pragma unroll
        for (int rr = 0; rr < 4; ++rr) {
          dA[uB >> 3][rgB * 4 + rr][uB & 7] = f2bf(dvB[rr]);
          outbuf[(rgB * 4 + rr) * 292 + 90 + uB] = dvB[rr];
        }
      }
    }
    BAR();

    // ---- S4: o1 = elu(deter@obs1d + emb_pre) ----
    {
      s16x8 ad4[7];
#pragma unroll
      for (int kt = 0; kt < 7; ++kt) ad4[kt] = *(const s16x8*)&dA[kt * 4 + kg][arow][0];
      int nI4 = (w < 5) ? 2 : 1;
#pragma unroll
      for (int ii = 0; ii < 2; ++ii) {
        if (ii < nI4) {
          int nt = w + 8 * ii;
          int colX = nt * 16 + arow;  // <= 207
          f32x4 acc = {0.f, 0.f, 0.f, 0.f};
#pragma unroll
          for (int q = 0; q < 6; ++q) {
            int tau = ni1 + 30 + ii * 6 + q;
            PREI(tau);
            s16x8 Bv = RING(tau);
            acc = MFMA16(ad4[q], Bv, acc);
            POSTI(tau);
          }
          const unsigned short* wp = (kg == 0) ? &l_o1dWT[colX][0] : &zblk[0];
          s16x8 B6 = *(const s16x8*)wp;
          acc = MFMA16(ad4[6], B6, acc);
          if (colX < 200) {
#pragma unroll
            for (int rr = 0; rr < 4; ++rr)
              xoA[colX >> 3][kg * 4 + rr][colX & 7] =
                  f2bf(eluf(acc[rr] + bf2f(e_[ii * 4 + rr])));
          }
        }
      }
    }
    BAR();

    // ---- S5: o = o1@obs2 + b (w<4) ----
    if (w < 4) {
      s16x8 a5[7];
#pragma unroll
      for (int kt = 0; kt < 7; ++kt) a5[kt] = *(const s16x8*)&xoA[kt * 4 + kg][arow][0];
      f32x4 acc = {b5, b5, b5, b5};
#pragma unroll
      for (int q = 0; q < 6; ++q) {
        int tau = ni1 + 30 + no1d + q;
        PREI(tau);
        s16x8 Bv = RING(tau);
        acc = MFMA16(a5[q], Bv, acc);
        POSTI(tau);
      }
      const unsigned short* wp = (kg == 0) ? &l_o2WT[col5][0] : &zblk[0];
      s16x8 B6 = *(const s16x8*)wp;
      acc = MFMA16(a5[6], B6, acc);
      if (col5 < 60) *(f32x4*)&s_o[col5][kg * 4] = acc;
    }
    BAR();

    // ---- S6: sampling + aux loads for t+1 ----
    MEMCLB;
    if (tid < 480) {
      int r = tid / 30, j = tid % 30;
      float qm = s_o[j][r];
      float qs = softpf(s_o[j + 30][r]) + 0.1f;
      float qst = qm + qs * eps_reg;
      outbuf[r * 292 + j] = qm;
      outbuf[r * 292 + 30 + j] = qs;
      outbuf[r * 292 + 60 + j] = qst;
      sA[j >> 3][r][j & 7] = f2bf(qst);
    }
    if (lane < 20) {
      int slot = w * 20 + lane, kk = slot % 10;
      sA[(30 + kk) >> 3][slot / 10][(30 + kk) & 7] = f2bf(act_reg);
    }
    {
      int tc = (t + 1 < T_) ? t + 1 : T_ - 1;     // eps/emb consumed at step t+1
      int ta = (t + 2 < T_) ? t + 2 : T_ - 1;     // action consumed at step t+2's S1
      if (tid < 480)
        eps_reg = eps_post[((size_t)tc * 1024 + b0 + tid / 30) * 30 + tid % 30];
      if (lane < 20) {
        int slot = w * 20 + lane;
        act_reg = action[((size_t)(b0 + slot / 10) * T_ + ta) * 10 + slot % 10];
      }
      size_t eb = ((size_t)tc * 1024 + b0) * 200;
#pragma unroll
      for (int rr = 0; rr < 4; ++rr) {
        e_[rr] = emb_pre[eb + (size_t)(kg * 4 + rr) * 200 + colA];
        e_[4 + rr] = emb_pre[eb + (size_t)(kg * 4 + rr) * 200 + colBc];
      }
    }
    BAR();

    // ---- S7: coalesced out stores (cols 0..291) ----
#pragma unroll
    for (int k2 = 0; k2 < 3; ++k2) {
      int idx = tid + k2 * 512;
      idx = idx > 1167 ? 1167 : idx;
      int row = idx / 73, ci = idx - row * 73;
      f32x4 v = *(const f32x4*)&outbuf[row * 292 + ci * 4];
      *(f32x4*)(out + ((size_t)(b0 + row) * T_ + t) * 580 + ci * 4) = v;
    }
    off = (off + Nreal) & 7;
  }
}

// --------------------------------------------------------------------------
// post_head: prior head (img2->elu->img3) over all T*B rows, time-parallel.
// Also copies deter to out[380..580).
// --------------------------------------------------------------------------
__global__ __launch_bounds__(256) void post_head(const float* __restrict__ eps_prior,
                                                 const float* __restrict__ img2_b,
                                                 const float* __restrict__ img3_b,
                                                 const unsigned short* __restrict__ pk,
                                                 float* __restrict__ out) {
  __shared__ __align__(16) unsigned short dAp[4][28][16][8];
  __shared__ __align__(16) unsigned short y1p[4][28][16][8];
  __shared__ __align__(16) float s_p[60][68];
  int b = blockIdx.x;
  int tid = threadIdx.x;
  int lane = tid & 63, w = tid >> 6, arow = lane & 15, kg = lane >> 4;

  // zero k-pad groups 25..27
  for (int i = tid; i < 1536; i += 256) {
    int mt = i / 384, rem = i % 384;
    int gidx = 25 + rem / 128, r2 = (rem % 128) / 8, j = rem & 7;
    dAp[mt][gidx][r2][j] = 0;
    y1p[mt][gidx][r2][j] = 0;
  }
  for (int i = tid; i < 12800; i += 256) {
    int row = i / 200, c = i % 200;
    float v = out[((size_t)(b * 64 + row)) * 580 + 90 + c];
    dAp[row >> 4][c >> 3][row & 15][c & 7] = f2bf(v);
  }
  __syncthreads();

  s16x8 ad[7];
#pragma unroll
  for (int kt = 0; kt < 7; ++kt) ad[kt] = *(const s16x8*)&dAp[w][kt * 4 + kg][arow][0];
#pragma unroll
  for (int nt = 0; nt < 13; ++nt) {
    int col = nt * 16 + arow;
    float bv = (col < 200) ? img2_b[col] : 0.f;
    f32x4 acc = {bv, bv, bv, bv};
#pragma unroll
    for (int kt = 0; kt < 7; ++kt) {
      s16x8 Bv = *(const s16x8*)(pk + OPI2 + (size_t)((nt * 7 + kt) * 512) + lane * 8);
      acc = __builtin_amdgcn_mfma_f32_16x16x32_bf16(ad[kt], Bv, acc, 0, 0, 0);
    }
    if (col < 200) {
#pragma unroll
      for (int rr = 0; rr < 4; ++rr)
        y1p[w][col >> 3][kg * 4 + rr][col & 7] = f2bf(eluf(acc[rr]));
    }
  }
  __syncthreads();

  s16x8 ay[7];
#pragma unroll
  for (int kt = 0; kt < 7; ++kt) ay[kt] = *(const s16x8*)&y1p[w][kt * 4 + kg][arow][0];
#pragma unroll
  for (int nt = 0; nt < 4; ++nt) {
    int col = nt * 16 + arow;
    float bv = (col < 60) ? img3_b[col] : 0.f;
    f32x4 acc = {bv, bv, bv, bv};
#pragma unroll
    for (int kt = 0; kt < 7; ++kt) {
      s16x8 Bv = *(const s16x8*)(pk + OPI3 + (size_t)((nt * 7 + kt) * 512) + lane * 8);
      acc = __builtin_amdgcn_mfma_f32_16x16x32_bf16(ay[kt], Bv, acc, 0, 0, 0);
    }
    if (col < 60) {
#pragma unroll
      for (int rr = 0; rr < 4; ++rr) s_p[col][w * 16 + kg * 4 + rr] = acc[rr];
    }
  }
  __syncthreads();

  for (int i = tid; i < 1920; i += 256) {
    int row = i / 30, j = i % 30;
    float pm = s_p[j][row];
    float ps = softpf(s_p[j + 30][row]) + 0.1f;
    float pst = pm + ps * eps_prior[((size_t)row * 1024 + b) * 30 + j];
    size_t ob = ((size_t)b * 64 + row) * 580;
    out[ob + 290 + j] = pm;
    out[ob + 320 + j] = ps;
    out[ob + 350 + j] = pst;
  }
  for (int i = tid; i < 6400; i += 256) {
    int row = i / 100, c2 = i % 100;
    size_t ob = ((size_t)b * 64 + row) * 580;
    *(float2*)&out[ob + 380 + c2 * 2] = *(const float2*)&out[ob + 90 + c2 * 2];
  }
}

extern "C" void kernel_launch(void* const* d_in, const int* in_sizes, int n_in,
                              void* d_out, int out_size, void* d_ws, size_t ws_size,
                              hipStream_t stream) {
  const float* embed    = (const float*)d_in[0];
  const float* action   = (const float*)d_in[1];
  const float* eps_post = (const float*)d_in[2];
  const float* eps_prior= (const float*)d_in[3];
  const float* img1_w   = (const float*)d_in[4];
  const float* img1_b   = (const float*)d_in[5];
  const float* gru_wi   = (const float*)d_in[6];
  const float* gru_wh   = (const float*)d_in[7];
  const float* gru_bi   = (const float*)d_in[8];
  const float* gru_bh   = (const float*)d_in[9];
  const float* img2_w   = (const float*)d_in[10];
  const float* img2_b   = (const float*)d_in[11];
  const float* img3_w   = (const float*)d_in[12];
  const float* img3_b   = (const float*)d_in[13];
  const float* obs1_w   = (const float*)d_in[14];
  const float* obs1_b   = (const float*)d_in[15];
  const float* obs2_w   = (const float*)d_in[16];
  const float* obs2_b   = (const float*)d_in[17];

  char* ws = (char*)d_ws;
  unsigned short* emb_pre = (unsigned short*)ws;
  unsigned short* pkw     = (unsigned short*)(ws + OFF_PK);
  unsigned short* swz     = (unsigned short*)(ws + OFF_SWZ);
  float* outp = (float*)d_out;

  prep_weights<<<256, 256, 0, stream>>>(img1_w, gru_wi, gru_wh, img2_w, img3_w,
                                        obs1_w, obs2_w, pkw, swz);
  emb_gemm<<<1024, 256, 0, stream>>>(embed, obs1_b, swz, emb_pre);
  scan_v5<<<64, 512, 0, stream>>>(action, eps_post, img1_b, gru_bi, gru_bh,
                                  obs2_b, pkw, emb_pre, outp);
  post_head<<<1024, 256, 0, stream>>>(eps_prior, img2_b, img3_b, pkw, outp);
}

// Round 6
// 996.169 us; speedup vs baseline: 2.5714x; 2.5714x over previous
//
#include <hip/hip_runtime.h>

#define T_ 64

typedef __attribute__((ext_vector_type(4))) float f32x4;
typedef __attribute__((ext_vector_type(8))) short s16x8;

__device__ __forceinline__ unsigned short f2bf(float f) {
  unsigned u = __float_as_uint(f);
  u = (u + 0x7FFFu + ((u >> 16) & 1u)) >> 16;
  return (unsigned short)u;
}
__device__ __forceinline__ float bf2f(unsigned short h) {
  return __uint_as_float(((unsigned)h) << 16);
}
__device__ __forceinline__ float eluf(float x) { return x > 0.f ? x : __expf(x) - 1.f; }
__device__ __forceinline__ float sigmf(float x) { return 1.f / (1.f + __expf(-x)); }
__device__ __forceinline__ float tanh_(float x) {
  float xx = fminf(fmaxf(x, -30.f), 30.f);
  float e = __expf(-2.f * xx);
  return (1.f - e) / (1.f + e);
}
__device__ __forceinline__ float softpf(float x) {
  return x > 20.f ? x : __logf(1.f + __expf(x));
}

// ---- pk layout (u16 offsets) ----
#define OPW1   0        // img1 kt0 only: 13*512 = 6656
#define OPWI   6656     // wi per-gate [3][13][6]: 119808
#define OPWH   126464   // wh per-gate [3][13][6]: 119808
#define OPO1D  246272   // obs1d [13][6]: 39936
#define OPO2   286208   // obs2 [4][6]: 12288
#define OPI2   298496   // img2 KT7 NT13: 46592 (post_head)
#define OPI3   345088   // img3 KT7 NT4: 14336 (post_head)
#define OWIWT  359424   // wi k=192..199 [3][208][8]: 4992
#define OWHWT  364416   // wh k-rem [3][208][8]: 4992
#define OO1DWT 369408   // [208][8]: 1664
#define OI1WT  371072   // img1 k=32..39 [208][8]: 1664
#define OO2WT  372736   // [64][8]: 512
#define PK_U16 373248

#define OFF_PK  26214400
#define OFF_SWZ 26960896

// B-frag pack: idx=((nt*KT+kt)*64+lane)*8+j ; W[k][n], n=nt*16+(lane&15),
// k=kt*32+(lane>>4)*8+j, zero-padded (validated layout).
__device__ void pack_mat(int idx, int stride, const float* __restrict__ W,
                         int K, int N, int KT, int NT, unsigned short* __restrict__ dst) {
  int total = KT * NT * 512;
  for (int i = idx; i < total; i += stride) {
    int j = i & 7, l = (i >> 3) & 63, rem = i >> 9;
    int kt = rem % KT, nt = rem / KT;
    int n = nt * 16 + (l & 15), k = kt * 32 + (l >> 4) * 8 + j;
    float v = (k < K && n < N) ? W[(size_t)k * N + n] : 0.f;
    dst[i] = f2bf(v);
  }
}

// per-gate GRU pack: idx=(((g*13+nt)*6+kt)*64+lane)*8+j ; col u=nt*16+(lane&15)
__device__ void pack_gate(int idx, int stride, const float* __restrict__ W,
                          unsigned short* __restrict__ dst) {
  int total = 3 * 13 * 6 * 512;
  for (int i = idx; i < total; i += stride) {
    int j = i & 7, l = (i >> 3) & 63, rem = i >> 9;
    int kt = rem % 6, rem2 = rem / 6, nt = rem2 % 13, g = rem2 / 13;
    int u = nt * 16 + (l & 15);
    int k = kt * 32 + (l >> 4) * 8 + j;   // < 192
    float v = (u < 200) ? W[(size_t)k * 600 + g * 200 + u] : 0.f;
    dst[i] = f2bf(v);
  }
}

__global__ void prep_weights(const float* __restrict__ w1, const float* __restrict__ wi,
                             const float* __restrict__ wh, const float* __restrict__ i2,
                             const float* __restrict__ i3, const float* __restrict__ obs1w,
                             const float* __restrict__ o2,
                             unsigned short* __restrict__ pk,
                             unsigned short* __restrict__ swz) {
  int idx = blockIdx.x * blockDim.x + threadIdx.x;
  int stride = gridDim.x * blockDim.x;
  pack_mat(idx, stride, w1, 40, 200, 1, 13, pk + OPW1);
  pack_gate(idx, stride, wi, pk + OPWI);
  pack_gate(idx, stride, wh, pk + OPWH);
  pack_mat(idx, stride, obs1w, 200, 200, 6, 13, pk + OPO1D);
  pack_mat(idx, stride, o2, 200, 60, 6, 4, pk + OPO2);
  pack_mat(idx, stride, i2, 200, 200, 7, 13, pk + OPI2);
  pack_mat(idx, stride, i3, 200, 60, 7, 4, pk + OPI3);
  for (int i = idx; i < 4992; i += stride) {
    int j = i & 7, c = (i >> 3) % 208, g = i / 1664;
    pk[OWIWT + i] = f2bf((c < 200) ? wi[(size_t)(192 + j) * 600 + g * 200 + c] : 0.f);
    pk[OWHWT + i] = f2bf((c < 200) ? wh[(size_t)(192 + j) * 600 + g * 200 + c] : 0.f);
  }
  for (int i = idx; i < 1664; i += stride) {
    int c = i >> 3, j = i & 7;
    pk[OO1DWT + i] = f2bf((c < 200) ? obs1w[(size_t)(192 + j) * 200 + c] : 0.f);
    pk[OI1WT + i]  = f2bf((c < 200) ? w1[(size_t)(32 + j) * 200 + c] : 0.f);
  }
  for (int i = idx; i < 512; i += stride) {
    int c = i >> 3, j = i & 7;
    pk[OO2WT + i] = f2bf((c < 60) ? o2[(size_t)(192 + j) * 60 + c] : 0.f);
  }
  // swz for emb_gemm (validated layout)
  for (int i = idx; i < 212992; i += stride) {
    int j = i & 7, l = (i >> 3) & 63, rem = i >> 9;
    int nt = rem % 13, kc = rem / 13;
    int k = kc * 32 + ((l >> 4) * 8) + j;
    int n = nt * 16 + (l & 15);
    float v = (n < 200) ? obs1w[(size_t)(200 + k) * 200 + n] : 0.0f;
    swz[i] = f2bf(v);
  }
}

// --------------------------------------------------------------------------
// emb_pre = embed @ obs1_w[200:,:] + obs1_b   (validated round-1 kernel)
// --------------------------------------------------------------------------
__global__ __launch_bounds__(256) void emb_gemm(const float* __restrict__ embed,
                                                const float* __restrict__ obs1b,
                                                const unsigned short* __restrict__ swz,
                                                unsigned short* __restrict__ emb_pre) {
  __shared__ __align__(16) unsigned short lds_A[64][40];
  int tid = threadIdx.x;
  int lane = tid & 63, w = tid >> 6;
  int R0 = blockIdx.x * 64;
  int tt = R0 >> 10;
  int bb = R0 & 1023;

  f32x4 acc[13];
#pragma unroll
  for (int nt = 0; nt < 13; ++nt) acc[nt] = (f32x4){0.f, 0.f, 0.f, 0.f};

  int i_row = tid >> 2, cg = tid & 3;
  const float* arow = embed + ((size_t)(bb + i_row) * 64 + tt) * 1024 + cg * 8;

  for (int kc = 0; kc < 32; ++kc) {
    __syncthreads();
    {
      const float* p = arow + kc * 32;
      f32x4 a0 = *(const f32x4*)p;
      f32x4 a1 = *(const f32x4*)(p + 4);
      unsigned short* dst = &lds_A[i_row][cg * 8];
      dst[0] = f2bf(a0[0]); dst[1] = f2bf(a0[1]); dst[2] = f2bf(a0[2]); dst[3] = f2bf(a0[3]);
      dst[4] = f2bf(a1[0]); dst[5] = f2bf(a1[1]); dst[6] = f2bf(a1[2]); dst[7] = f2bf(a1[3]);
    }
    __syncthreads();
    s16x8 af = *(const s16x8*)&lds_A[w * 16 + (lane & 15)][(lane >> 4) * 8];
    const unsigned short* bp = swz + (size_t)kc * 6656 + (size_t)lane * 8;
#pragma unroll
    for (int nt = 0; nt < 13; ++nt) {
      s16x8 bfv = *(const s16x8*)(bp + nt * 512);
      acc[nt] = __builtin_amdgcn_mfma_f32_16x16x32_bf16(af, bfv, acc[nt], 0, 0, 0);
    }
  }
  int r0 = R0 + w * 16 + ((lane >> 4) << 2);
  int c0 = lane & 15;
#pragma unroll
  for (int nt = 0; nt < 13; ++nt) {
    int n = nt * 16 + c0;
    if (n < 200) {
      float bv = obs1b[n];
#pragma unroll
      for (int rr = 0; rr < 4; ++rr)
        emb_pre[(size_t)(r0 + rr) * 200 + n] = f2bf(acc[nt][rr] + bv);
    }
  }
}

// --------------------------------------------------------------------------
// scan_v6: 64 blocks x 256 thr (4 waves, 1/SIMD). Weights resident in
// VGPR+LDS except wi + wh-gate-n streamed via static-slot 12-ring.
// --------------------------------------------------------------------------
#define WAITVC(n) asm volatile("s_waitcnt vmcnt(" #n ")" ::: "memory")
#define LGKM0  asm volatile("s_waitcnt lgkmcnt(0)" ::: "memory")
#define MEMCLB asm volatile("" ::: "memory")
#define BAR()  __builtin_amdgcn_s_barrier()
#define SCHED0 __builtin_amdgcn_sched_barrier(0)
#define MFMA16(A, B, C) __builtin_amdgcn_mfma_f32_16x16x32_bf16((A), (B), (C), 0, 0, 0)

typedef __attribute__((address_space(3))) unsigned int u32_lds;
typedef const __attribute__((address_space(1))) unsigned int u32_glb;

__device__ __forceinline__ void gll16(const unsigned short* g, unsigned short* l, int lane) {
  __builtin_amdgcn_global_load_lds((u32_glb*)(g + lane * 8), (u32_lds*)l, 16, 0, 0);
}

__global__ __launch_bounds__(256, 1) void scan_v6(
    const float* __restrict__ action, const float* __restrict__ eps_post,
    const float* __restrict__ img1_b, const float* __restrict__ gru_bi,
    const float* __restrict__ gru_bh, const float* __restrict__ obs2_b,
    const unsigned short* __restrict__ pk, const unsigned short* __restrict__ emb_pre,
    float* __restrict__ out) {

  __shared__ __align__(16) unsigned short ring[4][12][512];   // 48 KB
  __shared__ __align__(16) unsigned short l_w1[13 * 512];     // 13.3 KB
  __shared__ __align__(16) unsigned short l_o2[24 * 512];     // 24.6 KB
  __shared__ __align__(16) unsigned short l_wiWT[3][208][8];
  __shared__ __align__(16) unsigned short l_whWT[3][208][8];
  __shared__ __align__(16) unsigned short l_o1dWT[208][8];
  __shared__ __align__(16) unsigned short l_i1WT[208][8];
  __shared__ __align__(16) unsigned short l_o2WT[64][8];
  __shared__ __align__(16) unsigned short zblk[8];
  __shared__ __align__(16) unsigned short xoA[28][16][8];
  __shared__ __align__(16) unsigned short dA[28][16][8];
  __shared__ __align__(16) unsigned short sA[8][16][8];
  __shared__ __align__(16) float s_o[60][20];
  __shared__ __align__(16) float outbuf[16][292];
  __shared__ unsigned l_toff[4][96];

  const int tid = threadIdx.x, lane = tid & 63, w = tid >> 6;
  const int arow = lane & 15, kg = lane >> 4;
  const int b0 = blockIdx.x * 16;
  const int nug = (w == 0) ? 4 : 3;
  const int SW = nug * 24;                 // 96 (w0) / 72
  unsigned short* ringw = &ring[w][0][0];

  // ---------- prologue: LDS tables ----------
  for (int i = tid; i < 28 * 16 * 8; i += 256) { (&xoA[0][0][0])[i] = 0; (&dA[0][0][0])[i] = 0; }
  for (int i = tid; i < 8 * 16 * 8; i += 256) (&sA[0][0][0])[i] = 0;
  for (int i = tid; i < 13 * 512; i += 256) l_w1[i] = pk[OPW1 + i];
  for (int i = tid; i < 24 * 512; i += 256) l_o2[i] = pk[OPO2 + i];
  for (int i = tid; i < 4992; i += 256) (&l_wiWT[0][0][0])[i] = pk[OWIWT + i];
  for (int i = tid; i < 4992; i += 256) (&l_whWT[0][0][0])[i] = pk[OWHWT + i];
  for (int i = tid; i < 1664; i += 256) (&l_o1dWT[0][0])[i] = pk[OO1DWT + i];
  for (int i = tid; i < 1664; i += 256) (&l_i1WT[0][0])[i] = pk[OI1WT + i];
  for (int i = tid; i < 512; i += 256) (&l_o2WT[0][0])[i] = pk[OO2WT + i];
  if (tid < 8) zblk[tid] = 0;
  for (int i = tid; i < 4 * 96; i += 256) {
    int ww = i / 96, tau = i % 96;
    int iu = tau / 24, r2 = tau % 24, q = r2 / 6, kt = r2 % 6;
    int ug = ww + 4 * iu;
    unsigned off;
    if (q < 3) off = OPWI + (unsigned)((q * 13 + (ug <= 12 ? ug : 12)) * 6 + kt) * 512;
    else       off = OPWH + (unsigned)((2 * 13 + (ug <= 12 ? ug : 12)) * 6 + kt) * 512;
    l_toff[ww][tau] = off;
  }

  // ---------- resident weights (VGPR) ----------
  // slots: w0: 0..7 = wh gates r,z (iu*2+g), 8 = o1d nt12, 9 dummy
  //        w>0: 0..5 = wh (iu*2+g), 6..9 = o1d nt (w-1)+3i
  s16x8 wB[10][6];
#pragma unroll
  for (int s = 0; s < 10; ++s) {
    const unsigned short* base;
    if (w == 0) {
      if (s < 8) { int iu = s >> 1, g = s & 1; base = pk + OPWH + (size_t)((g * 13 + 4 * iu) * 6) * 512; }
      else if (s == 8) base = pk + OPO1D + (size_t)(12 * 6) * 512;
      else base = pk + OPO1D;
    } else {
      if (s < 6) { int iu = s >> 1, g = s & 1; base = pk + OPWH + (size_t)((g * 13 + (w + 4 * iu)) * 6) * 512; }
      else base = pk + OPO1D + (size_t)(((w - 1) + 3 * (s - 6)) * 6) * 512;
    }
#pragma unroll
    for (int kt = 0; kt < 6; ++kt)
      wB[s][kt] = *(const s16x8*)(base + (size_t)kt * 512 + lane * 8);
  }

  // ---------- biases ----------
  float bsum[4][2], bi2[4], bh2[4];
#pragma unroll
  for (int iu = 0; iu < 4; ++iu) {
    int u = (w + 4 * iu) * 16 + arow;
    bool vld = (iu < nug) && (u < 200);
    int uc = vld ? u : 0;
    float m = vld ? 1.f : 0.f;
    bsum[iu][0] = m * (gru_bi[uc] + gru_bh[uc]);
    bsum[iu][1] = m * (gru_bi[200 + uc] + gru_bh[200 + uc]);
    bi2[iu] = m * gru_bi[400 + uc];
    bh2[iu] = m * gru_bh[400 + uc];
  }
  float b1v[4];
#pragma unroll
  for (int i = 0; i < 4; ++i) {
    int nt = (i < 3) ? (w + 4 * i) : 12;
    int c = nt * 16 + arow;
    b1v[i] = (c < 200) ? img1_b[c] : 0.f;
  }
  float b5 = ((w * 16 + arow) < 60) ? obs2_b[w * 16 + arow] : 0.f;

  // ---------- aux t=0 ----------
  unsigned short e16[16];
#pragma unroll
  for (int i = 0; i < 4; ++i) {
    int nt4 = (w == 0) ? 12 : ((w - 1) + 3 * i);
    int c = nt4 * 16 + arow; int cc = (c < 200) ? c : 199;
#pragma unroll
    for (int rr = 0; rr < 4; ++rr)
      e16[i * 4 + rr] = emb_pre[((size_t)(b0 + kg * 4 + rr)) * 200 + cc];
  }
  float epsv[2];
  { int i1 = (tid + 256 < 480) ? tid + 256 : 479;
    epsv[0] = eps_post[((size_t)(b0 + tid / 30)) * 30 + tid % 30];
    epsv[1] = eps_post[((size_t)(b0 + i1 / 30)) * 30 + i1 % 30]; }
  float act0, actn;
  { int sl = (lane < 40) ? (w * 40 + lane) : (w * 40);
    act0 = action[((size_t)(b0 + sl / 10) * T_ + 0) * 10 + sl % 10];
    actn = action[((size_t)(b0 + sl / 10) * T_ + 1) * 10 + sl % 10]; }
  f32x4 dv[4];
#pragma unroll
  for (int iu = 0; iu < 4; ++iu) dv[iu] = (f32x4){0.f, 0.f, 0.f, 0.f};

  __syncthreads();
  if (lane < 40) {
    int sl = w * 40 + lane; int kk = sl % 10, r = sl / 10;
    sA[(30 + kk) >> 3][r][(30 + kk) & 7] = f2bf(act0);
  }
  // ring prefetch tiles 0..11
#pragma unroll
  for (int tt = 0; tt < 12; ++tt)
    gll16(pk + l_toff[w][tt], ringw + tt * 512, lane);
  WAITVC(0);
  __syncthreads();

  // ---------- T loop ----------
  for (int t = 0; t < T_; ++t) {
    // ===== S1: x = elu([stoch|act]@img1 + b1) =====
    {
      s16x8 a0 = *(const s16x8*)&sA[kg][arow][0];
      s16x8 a1 = *(const s16x8*)&sA[4 + kg][arow][0];
#pragma unroll
      for (int i = 0; i < 4; ++i) {
        if (i < 3 || w == 0) {
          int nt = (i < 3) ? (w + 4 * i) : 12;
          int c = nt * 16 + arow;
          s16x8 B0 = *(const s16x8*)&l_w1[nt * 512 + lane * 8];
          f32x4 acc = {b1v[i], b1v[i], b1v[i], b1v[i]};
          acc = MFMA16(a0, B0, acc);
          s16x8 B1 = *(const s16x8*)((kg == 0) ? &l_i1WT[c][0] : &zblk[0]);
          acc = MFMA16(a1, B1, acc);
          if (c < 200) {
#pragma unroll
            for (int rr = 0; rr < 4; ++rr)
              xoA[c >> 3][kg * 4 + rr][c & 7] = f2bf(eluf(acc[rr]));
          }
        }
      }
    }
    LGKM0; BAR();   // B1: xA ready

    // ===== S2: gates (wi streamed + wh regs/stream) + fused GRU =====
    {
#pragma unroll
      for (int iu = 0; iu < 4; ++iu) {
        if (iu < 3 || w == 0) {
          const int uu = (w + 4 * iu) * 16 + arow;
          const int uuc = (uu < 208) ? uu : 207;
          s16x8 ax[6], ad[6];
#pragma unroll
          for (int kt = 0; kt < 6; ++kt) {
            ax[kt] = *(const s16x8*)&xoA[kt * 4 + kg][arow][0];
            ad[kt] = *(const s16x8*)&dA[kt * 4 + kg][arow][0];
          }
          s16x8 ax6 = *(const s16x8*)&xoA[24 + kg][arow][0];
          s16x8 ad6 = *(const s16x8*)&dA[24 + kg][arow][0];
          f32x4 gv[2], gin, ghn;
#pragma unroll
          for (int q = 0; q < 4; ++q) {
            const int beta = iu * 4 + q;
            if (beta < 2) { WAITVC(30); } else { WAITVC(6); }
            float b = (q < 2) ? bsum[iu][q & 1] : ((q == 2) ? bi2[iu] : bh2[iu]);
            f32x4 acc = {b, b, b, b};
#pragma unroll
            for (int kt = 0; kt < 6; ++kt) {
              const int slot = (beta * 6 + kt) % 12;
              s16x8 Bv = *(const s16x8*)(ringw + slot * 512 + lane * 8);
              acc = MFMA16((q == 3) ? ad[kt] : ax[kt], Bv, acc);
            }
            MEMCLB; SCHED0;
            // reissue just-consumed slots with tiles beta*6+12 (mod SW)
#pragma unroll
            for (int k2 = 0; k2 < 6; ++k2) {
              const int ttc = beta * 6 + 12 + k2;
              int tm = (ttc >= SW) ? ttc - SW : ttc;
              gll16(pk + l_toff[w][tm], ringw + ((ttc % 12) * 512), lane);
            }
            if (q < 2) {
              { const unsigned short* wp = (kg == 0) ? &l_wiWT[q][uuc][0] : &zblk[0];
                acc = MFMA16(ax6, *(const s16x8*)wp, acc); }
              const int s_ = iu * 2 + q;
#pragma unroll
              for (int kt = 0; kt < 6; ++kt) acc = MFMA16(ad[kt], wB[s_][kt], acc);
              { const unsigned short* wp = (kg == 0) ? &l_whWT[q][uuc][0] : &zblk[0];
                acc = MFMA16(ad6, *(const s16x8*)wp, acc); }
              gv[q] = acc;
            } else if (q == 2) {
              const unsigned short* wp = (kg == 0) ? &l_wiWT[2][uuc][0] : &zblk[0];
              gin = MFMA16(ax6, *(const s16x8*)wp, acc);
            } else {
              const unsigned short* wp = (kg == 0) ? &l_whWT[2][uuc][0] : &zblk[0];
              ghn = MFMA16(ad6, *(const s16x8*)wp, acc);
            }
          }
          // GRU on f32 register carry
#pragma unroll
          for (int rr = 0; rr < 4; ++rr) {
            float r = sigmf(gv[0][rr]);
            float z = sigmf(gv[1][rr]);
            float n = tanh_(gin[rr] + r * ghn[rr]);
            dv[iu][rr] = (1.f - z) * n + z * dv[iu][rr];
          }
          if (uu < 200) {
#pragma unroll
            for (int rr = 0; rr < 4; ++rr) outbuf[kg * 4 + rr][90 + uu] = dv[iu][rr];
          }
        }
      }
    }
    LGKM0; BAR();   // B2: all reads of old dA complete

    // S2b: publish new deter
#pragma unroll
    for (int iu = 0; iu < 4; ++iu) {
      if (iu < 3 || w == 0) {
        int uu = (w + 4 * iu) * 16 + arow;
        if (uu < 200) {
#pragma unroll
          for (int rr = 0; rr < 4; ++rr)
            dA[uu >> 3][kg * 4 + rr][uu & 7] = f2bf(dv[iu][rr]);
        }
      }
    }
    LGKM0; BAR();   // B3: dA ready

    // ===== S4: o1 = elu(deter@obs1d + emb) -> xoA =====
    {
      s16x8 ad4[6];
#pragma unroll
      for (int kt = 0; kt < 6; ++kt) ad4[kt] = *(const s16x8*)&dA[kt * 4 + kg][arow][0];
      s16x8 ad46 = *(const s16x8*)&dA[24 + kg][arow][0];
      if (w == 0) {
        int c = 192 + arow;
        f32x4 acc = {0.f, 0.f, 0.f, 0.f};
#pragma unroll
        for (int kt = 0; kt < 6; ++kt) acc = MFMA16(ad4[kt], wB[8][kt], acc);
        { const unsigned short* wp = (kg == 0) ? &l_o1dWT[c][0] : &zblk[0];
          acc = MFMA16(ad46, *(const s16x8*)wp, acc); }
        if (c < 200) {
#pragma unroll
          for (int rr = 0; rr < 4; ++rr)
            xoA[c >> 3][kg * 4 + rr][c & 7] = f2bf(eluf(acc[rr] + bf2f(e16[rr])));
        }
      } else {
#pragma unroll
        for (int i = 0; i < 4; ++i) {
          int c = ((w - 1) + 3 * i) * 16 + arow;   // <= 191
          f32x4 acc = {0.f, 0.f, 0.f, 0.f};
#pragma unroll
          for (int kt = 0; kt < 6; ++kt) acc = MFMA16(ad4[kt], wB[6 + i][kt], acc);
          { const unsigned short* wp = (kg == 0) ? &l_o1dWT[c][0] : &zblk[0];
            acc = MFMA16(ad46, *(const s16x8*)wp, acc); }
#pragma unroll
          for (int rr = 0; rr < 4; ++rr)
            xoA[c >> 3][kg * 4 + rr][c & 7] = f2bf(eluf(acc[rr] + bf2f(e16[i * 4 + rr])));
        }
      }
    }
    LGKM0; BAR();   // B4: o1 ready

    // ===== S5: o = o1@obs2 + b5 =====
    {
      s16x8 a5[6];
#pragma unroll
      for (int kt = 0; kt < 6; ++kt) a5[kt] = *(const s16x8*)&xoA[kt * 4 + kg][arow][0];
      s16x8 a56 = *(const s16x8*)&xoA[24 + kg][arow][0];
      int c5 = w * 16 + arow;
      f32x4 acc = {b5, b5, b5, b5};
#pragma unroll
      for (int kt = 0; kt < 6; ++kt) {
        s16x8 Bv = *(const s16x8*)&l_o2[(w * 6 + kt) * 512 + lane * 8];
        acc = MFMA16(a5[kt], Bv, acc);
      }
      { const unsigned short* wp = (kg == 0) ? &l_o2WT[c5][0] : &zblk[0];
        acc = MFMA16(a56, *(const s16x8*)wp, acc); }
      if (c5 < 60) *(f32x4*)&s_o[c5][kg * 4] = acc;
    }
    LGKM0; BAR();   // B5: s_o ready

    // ===== S6: sampling + aux prefetch for t+1 =====
    {
#pragma unroll
      for (int rep = 0; rep < 2; ++rep) {
        int it = tid + rep * 256;
        bool v = it < 480;
        int itc = v ? it : 479;
        int r = itc / 30, j = itc % 30;
        float qm = s_o[j][r];
        float qs = softpf(s_o[j + 30][r]) + 0.1f;
        float qst = qm + qs * epsv[rep];
        if (v) {
          outbuf[r][j] = qm; outbuf[r][30 + j] = qs; outbuf[r][60 + j] = qst;
          sA[j >> 3][r][j & 7] = f2bf(qst);
        }
      }
      if (lane < 40) {
        int sl = w * 40 + lane; int kk = sl % 10, r = sl / 10;
        sA[(30 + kk) >> 3][r][(30 + kk) & 7] = f2bf(actn);
      }
      int tc = (t + 1 < T_) ? t + 1 : T_ - 1;
      int ta = (t + 2 < T_) ? t + 2 : T_ - 1;
#pragma unroll
      for (int i = 0; i < 4; ++i) {
        int nt4 = (w == 0) ? 12 : ((w - 1) + 3 * i);
        int c = nt4 * 16 + arow; int cc = (c < 200) ? c : 199;
#pragma unroll
        for (int rr = 0; rr < 4; ++rr)
          e16[i * 4 + rr] = emb_pre[((size_t)tc * 1024 + b0 + kg * 4 + rr) * 200 + cc];
      }
      { int i1 = (tid + 256 < 480) ? tid + 256 : 479;
        epsv[0] = eps_post[((size_t)tc * 1024 + b0 + tid / 30) * 30 + tid % 30];
        epsv[1] = eps_post[((size_t)tc * 1024 + b0 + i1 / 30) * 30 + i1 % 30]; }
      { int sl = (lane < 40) ? (w * 40 + lane) : (w * 40);
        actn = action[((size_t)(b0 + sl / 10) * T_ + ta) * 10 + sl % 10]; }
    }
    LGKM0; BAR();   // B6: outbuf/sA complete

    // ===== S7: coalesced out stores (cols 0..291) =====
#pragma unroll
    for (int k2 = 0; k2 < 5; ++k2) {
      int idx = tid + k2 * 256; idx = (idx < 1168) ? idx : 1167;
      int row = idx / 73, ci = idx - row * 73;
      f32x4 v = *(const f32x4*)&outbuf[row][ci * 4];
      *(f32x4*)(out + ((size_t)(b0 + row) * T_ + t) * 580 + ci * 4) = v;
    }
  }
}

// --------------------------------------------------------------------------
// post_head: prior head (img2->elu->img3), time-parallel; copies deter dup.
// --------------------------------------------------------------------------
__global__ __launch_bounds__(256) void post_head(const float* __restrict__ eps_prior,
                                                 const float* __restrict__ img2_b,
                                                 const float* __restrict__ img3_b,
                                                 const unsigned short* __restrict__ pk,
                                                 float* __restrict__ out) {
  __shared__ __align__(16) unsigned short dAp[4][28][16][8];
  __shared__ __align__(16) unsigned short y1p[4][28][16][8];
  __shared__ __align__(16) float s_p[60][68];
  int b = blockIdx.x;
  int tid = threadIdx.x;
  int lane = tid & 63, w = tid >> 6, arow = lane & 15, kg = lane >> 4;

  for (int i = tid; i < 1536; i += 256) {
    int mt = i / 384, rem = i % 384;
    int gidx = 25 + rem / 128, r2 = (rem % 128) / 8, j = rem & 7;
    dAp[mt][gidx][r2][j] = 0;
    y1p[mt][gidx][r2][j] = 0;
  }
  for (int i = tid; i < 12800; i += 256) {
    int row = i / 200, c = i % 200;
    float v = out[((size_t)(b * 64 + row)) * 580 + 90 + c];
    dAp[row >> 4][c >> 3][row & 15][c & 7] = f2bf(v);
  }
  __syncthreads();

  s16x8 ad[7];
#pragma unroll
  for (int kt = 0; kt < 7; ++kt) ad[kt] = *(const s16x8*)&dAp[w][kt * 4 + kg][arow][0];
#pragma unroll
  for (int nt = 0; nt < 13; ++nt) {
    int col = nt * 16 + arow;
    float bv = (col < 200) ? img2_b[col] : 0.f;
    f32x4 acc = {bv, bv, bv, bv};
#pragma unroll
    for (int kt = 0; kt < 7; ++kt) {
      s16x8 Bv = *(const s16x8*)(pk + OPI2 + (size_t)((nt * 7 + kt) * 512) + lane * 8);
      acc = __builtin_amdgcn_mfma_f32_16x16x32_bf16(ad[kt], Bv, acc, 0, 0, 0);
    }
    if (col < 200) {
#pragma unroll
      for (int rr = 0; rr < 4; ++rr)
        y1p[w][col >> 3][kg * 4 + rr][col & 7] = f2bf(eluf(acc[rr]));
    }
  }
  __syncthreads();

  s16x8 ay[7];
#pragma unroll
  for (int kt = 0; kt < 7; ++kt) ay[kt] = *(const s16x8*)&y1p[w][kt * 4 + kg][arow][0];
#pragma unroll
  for (int nt = 0; nt < 4; ++nt) {
    int col = nt * 16 + arow;
    float bv = (col < 60) ? img3_b[col] : 0.f;
    f32x4 acc = {bv, bv, bv, bv};
#pragma unroll
    for (int kt = 0; kt < 7; ++kt) {
      s16x8 Bv = *(const s16x8*)(pk + OPI3 + (size_t)((nt * 7 + kt) * 512) + lane * 8);
      acc = __builtin_amdgcn_mfma_f32_16x16x32_bf16(ay[kt], Bv, acc, 0, 0, 0);
    }
    if (col < 60) {
#pragma unroll
      for (int rr = 0; rr < 4; ++rr) s_p[col][w * 16 + kg * 4 + rr] = acc[rr];
    }
  }
  __syncthreads();

  for (int i = tid; i < 1920; i += 256) {
    int row = i / 30, j = i % 30;
    float pm = s_p[j][row];
    float ps = softpf(s_p[j + 30][row]) + 0.1f;
    float pst = pm + ps * eps_prior[((size_t)row * 1024 + b) * 30 + j];
    size_t ob = ((size_t)b * 64 + row) * 580;
    out[ob + 290 + j] = pm;
    out[ob + 320 + j] = ps;
    out[ob + 350 + j] = pst;
  }
  for (int i = tid; i < 6400; i += 256) {
    int row = i / 100, c2 = i % 100;
    size_t ob = ((size_t)b * 64 + row) * 580;
    *(float2*)&out[ob + 380 + c2 * 2] = *(const float2*)&out[ob + 90 + c2 * 2];
  }
}

extern "C" void kernel_launch(void* const* d_in, const int* in_sizes, int n_in,
                              void* d_out, int out_size, void* d_ws, size_t ws_size,
                              hipStream_t stream) {
  const float* embed    = (const float*)d_in[0];
  const float* action   = (const float*)d_in[1];
  const float* eps_post = (const float*)d_in[2];
  const float* eps_prior= (const float*)d_in[3];
  const float* img1_w   = (const float*)d_in[4];
  const float* img1_b   = (const float*)d_in[5];
  const float* gru_wi   = (const float*)d_in[6];
  const float* gru_wh   = (const float*)d_in[7];
  const float* gru_bi   = (const float*)d_in[8];
  const float* gru_bh   = (const float*)d_in[9];
  const float* img2_w   = (const float*)d_in[10];
  const float* img2_b   = (const float*)d_in[11];
  const float* img3_w   = (const float*)d_in[12];
  const float* img3_b   = (const float*)d_in[13];
  const float* obs1_w   = (const float*)d_in[14];
  const float* obs1_b   = (const float*)d_in[15];
  const float* obs2_w   = (const float*)d_in[16];
  const float* obs2_b   = (const float*)d_in[17];

  char* ws = (char*)d_ws;
  unsigned short* emb_pre = (unsigned short*)ws;
  unsigned short* pkw     = (unsigned short*)(ws + OFF_PK);
  unsigned short* swz     = (unsigned short*)(ws + OFF_SWZ);
  float* outp = (float*)d_out;

  prep_weights<<<256, 256, 0, stream>>>(img1_w, gru_wi, gru_wh, img2_w, img3_w,
                                        obs1_w, obs2_w, pkw, swz);
  emb_gemm<<<1024, 256, 0, stream>>>(embed, obs1_b, swz, emb_pre);
  scan_v6<<<64, 256, 0, stream>>>(action, eps_post, img1_b, gru_bi, gru_bh,
                                  obs2_b, pkw, emb_pre, outp);
  post_head<<<1024, 256, 0, stream>>>(eps_prior, img2_b, img3_b, pkw, outp);
}